// Round 1
// baseline (169.684 us; speedup 1.0000x reference)
//
#include <hip/hip_runtime.h>

typedef __attribute__((ext_vector_type(4))) float f32x4;
typedef __attribute__((ext_vector_type(8))) short bf16x8;

__device__ __forceinline__ unsigned short f2bf(float f) {
  unsigned int u = __builtin_bit_cast(unsigned int, f);
  u += 0x7FFFu + ((u >> 16) & 1u);   // RTNE
  return (unsigned short)(u >> 16);
}

// ---- K0a: P[b][h] = b_attn[h] + dot(W_attn[h, 0:512], hidden[b, :])
__global__ __launch_bounds__(256) void k_prep_p(
    const float* __restrict__ hidden, const float* __restrict__ W,
    const float* __restrict__ bias, float* __restrict__ P) {
  __shared__ float hsh[512];
  const int b = blockIdx.x;
  for (int i = threadIdx.x; i < 512; i += 256) hsh[i] = hidden[b * 512 + i];
  __syncthreads();
  for (int h = threadIdx.x; h < 512; h += 256) {
    const float* wr = W + (long)h * 1536;
    float s = 0.f;
#pragma unroll 4
    for (int f = 0; f < 512; f += 4) {
      float4 wv = *reinterpret_cast<const float4*>(wr + f);
      s += wv.x * hsh[f] + wv.y * hsh[f + 1] + wv.z * hsh[f + 2] + wv.w * hsh[f + 3];
    }
    P[b * 512 + h] = bias[h] + s;
  }
}

// ---- K0b: W2t[kb][h][kk] = bf16(W_attn[h][512 + kb*32 + kk]),  kb<32, h<512, kk<32
__global__ __launch_bounds__(256) void k_prep_w(
    const float* __restrict__ W, unsigned short* __restrict__ W2t) {
  const int id = blockIdx.x * 256 + threadIdx.x;  // 65536 threads, 8 elems each
  const int kk8 = (id & 3) * 8;
  const int h = (id >> 2) & 511;
  const int kb = id >> 11;
  const float* src = W + (long)h * 1536 + 512 + kb * 32 + kk8;
  float4 a = *reinterpret_cast<const float4*>(src);
  float4 c = *reinterpret_cast<const float4*>(src + 4);
  union { unsigned short u[8]; bf16x8 v; } o;
  o.u[0] = f2bf(a.x); o.u[1] = f2bf(a.y); o.u[2] = f2bf(a.z); o.u[3] = f2bf(a.w);
  o.u[4] = f2bf(c.x); o.u[5] = f2bf(c.y); o.u[6] = f2bf(c.z); o.u[7] = f2bf(c.w);
  *reinterpret_cast<bf16x8*>(W2t + (long)kb * 16384 + h * 32 + kk8) = o.v;
}

// ---- K1: main fused GEMM + tanh + v-reduce -> logits[65536]
// grid 1024 (BM=64 rows each), 256 threads (4 waves, wave w owns cols w*128..+127)
__global__ __launch_bounds__(256, 2) void k_main(
    const float* __restrict__ enc, const short* __restrict__ W2t,
    const float* __restrict__ P, const float* __restrict__ v,
    float* __restrict__ logits) {
  __shared__ short encT[64 * 32];      // [row][k] bf16 tile, 4 KB
  __shared__ float attred[64][4];

  const int tid = threadIdx.x;
  const int lane = tid & 63;
  const int w = tid >> 6;
  const int hl = lane & 15;
  const int kg = lane >> 4;
  const long rowbase = (long)blockIdx.x * 64;
  const int b = (int)(rowbase >> 12);  // 4096 rows per batch, 64 | 4096

  // staging: thread t loads enc row (t/4), 8 consecutive floats at col (t%4)*8
  const int st_r = tid >> 2;
  const int st_c = (tid & 3) * 8;
  const float* gsrc = enc + (rowbase + st_r) * 1024 + st_c;

  float4 p0 = *reinterpret_cast<const float4*>(gsrc);
  float4 p1 = *reinterpret_cast<const float4*>(gsrc + 4);

  f32x4 acc[4][8];
#pragma unroll
  for (int mi = 0; mi < 4; ++mi)
#pragma unroll
    for (int ni = 0; ni < 8; ++ni) acc[mi][ni] = (f32x4){0.f, 0.f, 0.f, 0.f};

  for (int kb = 0; kb < 32; ++kb) {
    __syncthreads();  // previous iter's a-frag reads done before overwrite
    union { unsigned short u[8]; bf16x8 vv; } pk;
    pk.u[0] = f2bf(p0.x); pk.u[1] = f2bf(p0.y); pk.u[2] = f2bf(p0.z); pk.u[3] = f2bf(p0.w);
    pk.u[4] = f2bf(p1.x); pk.u[5] = f2bf(p1.y); pk.u[6] = f2bf(p1.z); pk.u[7] = f2bf(p1.w);
    *reinterpret_cast<bf16x8*>(&encT[st_r * 32 + st_c]) = pk.vv;
    if (kb < 31) {  // prefetch next K-slab
      p0 = *reinterpret_cast<const float4*>(gsrc + (kb + 1) * 32);
      p1 = *reinterpret_cast<const float4*>(gsrc + (kb + 1) * 32 + 4);
    }
    __syncthreads();

    bf16x8 af[4];
#pragma unroll
    for (int mi = 0; mi < 4; ++mi)
      af[mi] = *reinterpret_cast<const bf16x8*>(&encT[(mi * 16 + hl) * 32 + kg * 8]);

    const short* wb = W2t + (long)kb * 16384 + (w * 128 + hl) * 32 + kg * 8;
    bf16x8 bfr[8];
#pragma unroll
    for (int ni = 0; ni < 8; ++ni)
      bfr[ni] = *reinterpret_cast<const bf16x8*>(wb + ni * 512);  // ni*16 rows * 32

#pragma unroll
    for (int ni = 0; ni < 8; ++ni)
#pragma unroll
      for (int mi = 0; mi < 4; ++mi)
        acc[mi][ni] = __builtin_amdgcn_mfma_f32_16x16x32_bf16(af[mi], bfr[ni],
                                                              acc[mi][ni], 0, 0, 0);
  }

  // epilogue: x = acc + P[b][h]; e = tanh(x); part += v[h]*e
  float part[4][4];
#pragma unroll
  for (int mi = 0; mi < 4; ++mi)
#pragma unroll
    for (int r = 0; r < 4; ++r) part[mi][r] = 0.f;

#pragma unroll
  for (int ni = 0; ni < 8; ++ni) {
    const int h = w * 128 + ni * 16 + hl;
    const float ph = P[b * 512 + h];
    const float vh = v[h];
#pragma unroll
    for (int mi = 0; mi < 4; ++mi)
#pragma unroll
      for (int r = 0; r < 4; ++r) {
        float x = acc[mi][ni][r] + ph;
        float e = __expf(2.f * x);                    // tanh = 1 - 2/(e^{2x}+1)
        part[mi][r] += vh * (1.f - 2.f * __frcp_rn(e + 1.f));
      }
  }
  // reduce over the 16 lanes (hl) sharing each output row
#pragma unroll
  for (int off = 1; off < 16; off <<= 1)
#pragma unroll
    for (int mi = 0; mi < 4; ++mi)
#pragma unroll
      for (int r = 0; r < 4; ++r)
        part[mi][r] += __shfl_xor(part[mi][r], off, 16);

  if (hl == 0) {
#pragma unroll
    for (int mi = 0; mi < 4; ++mi)
#pragma unroll
      for (int r = 0; r < 4; ++r)
        attred[mi * 16 + kg * 4 + r][w] = part[mi][r];
  }
  __syncthreads();
  if (tid < 64)
    logits[rowbase + tid] =
        attred[tid][0] + attred[tid][1] + attred[tid][2] + attred[tid][3];
}

// ---- K2: softmax over S=4096 per batch row
__global__ __launch_bounds__(256) void k_softmax(
    const float* __restrict__ logits, float* __restrict__ out) {
  const int b = blockIdx.x;
  const int t = threadIdx.x;
  const int wid = t >> 6, lane = t & 63;
  const float* L = logits + b * 4096;
  __shared__ float rmax[4], rsum[4];
  float lv[16];
  float m = -1e30f;
#pragma unroll
  for (int i = 0; i < 16; ++i) {
    lv[i] = L[t + i * 256];
    m = fmaxf(m, lv[i]);
  }
#pragma unroll
  for (int off = 32; off >= 1; off >>= 1) m = fmaxf(m, __shfl_xor(m, off));
  if (lane == 0) rmax[wid] = m;
  __syncthreads();
  m = fmaxf(fmaxf(rmax[0], rmax[1]), fmaxf(rmax[2], rmax[3]));
  float s = 0.f;
#pragma unroll
  for (int i = 0; i < 16; ++i) {
    lv[i] = __expf(lv[i] - m);
    s += lv[i];
  }
#pragma unroll
  for (int off = 32; off >= 1; off >>= 1) s += __shfl_xor(s, off);
  if (lane == 0) rsum[wid] = s;
  __syncthreads();
  s = rsum[0] + rsum[1] + rsum[2] + rsum[3];
  float inv = 1.0f / s;
#pragma unroll
  for (int i = 0; i < 16; ++i) out[b * 4096 + t + i * 256] = lv[i] * inv;
}

extern "C" void kernel_launch(void* const* d_in, const int* in_sizes, int n_in,
                              void* d_out, int out_size, void* d_ws, size_t ws_size,
                              hipStream_t stream) {
  const float* hidden = (const float*)d_in[0];   // [16,512]
  const float* enc    = (const float*)d_in[1];   // [16,4096,1024]
  const float* W      = (const float*)d_in[2];   // [512,1536]
  const float* bias   = (const float*)d_in[3];   // [512]
  const float* v      = (const float*)d_in[4];   // [512]
  float* out = (float*)d_out;                    // [16,4096]

  char* ws = (char*)d_ws;
  float* P = (float*)ws;                                   // 32 KB
  unsigned short* W2t = (unsigned short*)(ws + 32768);     // 1 MB
  float* logits = (float*)(ws + 32768 + 1048576);          // 256 KB

  k_prep_p<<<16, 256, 0, stream>>>(hidden, W, bias, P);
  k_prep_w<<<256, 256, 0, stream>>>(W, W2t);
  k_main<<<1024, 256, 0, stream>>>(enc, (const short*)W2t, P, v, logits);
  k_softmax<<<16, 256, 0, stream>>>(logits, out);
}